// Round 7
// baseline (250.196 us; speedup 1.0000x reference)
//
#include <hip/hip_runtime.h>
#include <cstdint>

#define T_DIM 128
#define C_DIM 256
#define HW_DIM 1024
#define B_DIM 16
#define NJR 8       // register j-blocks (64 cols each) in sinkhorn fast path
#define PARTC 640   // max compacted cols handled by fast path
#define CHK 10      // convergence check period
#define TOL 2e-6f   // relative u-change tolerance
#define LDP 72      // padded LDS row pitch (bf16 elems) for 64-wide tiles

typedef __bf16 bf16x8 __attribute__((ext_vector_type(8)));
typedef float f32x4 __attribute__((ext_vector_type(4)));

__device__ __forceinline__ float fast_rcp(float x) {
  return __builtin_amdgcn_rcpf(x);
}

__device__ __forceinline__ unsigned short f2bf(float x) {  // RTNE fp32->bf16
  unsigned u = __float_as_uint(x);
  u += 0x7fffu + ((u >> 16) & 1u);
  return (unsigned short)(u >> 16);
}
__device__ __forceinline__ float bf2f(unsigned short h) {
  return __uint_as_float((unsigned)h << 16);
}

// ---------- prep: per-batch fg count + compact position map ----------
__global__ __launch_bounds__(256) void prep_kernel(const int* __restrict__ Ms,
                                                   int* __restrict__ nfg,
                                                   int* __restrict__ pos)
{
  const int b = blockIdx.x, tid = threadIdx.x;
  const int4 m4 = *(const int4*)(Ms + b * HW_DIM + tid * 4);
  const int c = m4.x + m4.y + m4.z + m4.w;
  const int lane = tid & 63, w = tid >> 6;
  int pre = c;
  #pragma unroll
  for (int o = 1; o < 64; o <<= 1) { int t = __shfl_up(pre, (unsigned)o); if (lane >= o) pre += t; }
  __shared__ int wtot[4];
  if (lane == 63) wtot[w] = pre;
  __syncthreads();
  int base = 0;
  #pragma unroll
  for (int i = 0; i < 4; i++) if (i < w) base += wtot[i];
  const int excl = base + pre - c;
  if (tid == 0) nfg[b] = wtot[0] + wtot[1] + wtot[2] + wtot[3];
  int p = excl;
  const int mm[4] = {m4.x, m4.y, m4.z, m4.w};
  #pragma unroll
  for (int q = 0; q < 4; q++) {
    pos[b * HW_DIM + tid * 4 + q] = mm[q] ? p : -1;
    p += mm[q];
  }
}

// ---------- bias-fold vectors: w0 = b_aQ@W_sK^T, wq = W_aQ@b_sK, s0 = b_aQ.b_sK ----------
__global__ __launch_bounds__(256) void wvec_kernel(
    const float* __restrict__ W_aQ, const float* __restrict__ b_aQ,
    const float* __restrict__ W_sK, const float* __restrict__ b_sK,
    float* __restrict__ w0, float* __restrict__ wq, float* __restrict__ s0)
{
  const int wid = blockIdx.x * 4 + (threadIdx.x >> 6);
  const int lane = threadIdx.x & 63;
  if (wid > 512) return;
  float acc = 0.f;
  if (wid < 256) {
    #pragma unroll 4
    for (int j = 0; j < 16; j++) { int h = lane + 64 * j; acc = fmaf(b_aQ[h], W_sK[(size_t)wid * 1024 + h], acc); }
  } else if (wid < 512) {
    const int c = wid - 256;
    #pragma unroll 4
    for (int j = 0; j < 16; j++) { int h = lane + 64 * j; acc = fmaf(W_aQ[(size_t)c * 1024 + h], b_sK[h], acc); }
  } else {
    #pragma unroll 4
    for (int j = 0; j < 16; j++) { int h = lane + 64 * j; acc = fmaf(b_aQ[h], b_sK[h], acc); }
  }
  #pragma unroll
  for (int o = 32; o; o >>= 1) acc += __shfl_xor(acc, o);
  if (lane == 0) {
    if (wid < 256) w0[wid] = acc;
    else if (wid < 512) wq[wid - 256] = acc;
    else s0[0] = acc;
  }
}

// ---------- qb[r] = F_a[r,:].wq + s0 ----------
__global__ __launch_bounds__(256) void qb_kernel(const float* __restrict__ F_a,
    const float* __restrict__ wq, const float* __restrict__ s0, float* __restrict__ qb)
{
  const int r = blockIdx.x * 4 + (threadIdx.x >> 6);
  const int lane = threadIdx.x & 63;
  float acc = 0.f;
  #pragma unroll
  for (int j = 0; j < 4; j++) { int c = lane + 64 * j; acc = fmaf(F_a[(size_t)r * 256 + c], wq[c], acc); }
  #pragma unroll
  for (int o = 32; o; o >>= 1) acc += __shfl_xor(acc, o);
  if (lane == 0) qb[r] = acc + s0[0];
}

// ---------- fp32 -> (hi, lo) bf16 split (8 elems/thread) ----------
__global__ __launch_bounds__(256) void split_kernel(const float* __restrict__ S,
    unsigned short* __restrict__ Dh, unsigned short* __restrict__ Dl, int n8)
{
  const int i = blockIdx.x * 256 + threadIdx.x;
  if (i >= n8) return;
  const float4 x0 = ((const float4*)S)[2 * i];
  const float4 x1 = ((const float4*)S)[2 * i + 1];
  const float xs[8] = {x0.x, x0.y, x0.z, x0.w, x1.x, x1.y, x1.z, x1.w};
  unsigned hs[8], ls[8];
  #pragma unroll
  for (int q = 0; q < 8; q++) {
    const unsigned short h = f2bf(xs[q]);
    hs[q] = h;
    ls[q] = f2bf(xs[q] - bf2f(h));
  }
  uint4 oh, ol;
  oh.x = hs[0] | (hs[1] << 16); oh.y = hs[2] | (hs[3] << 16);
  oh.z = hs[4] | (hs[5] << 16); oh.w = hs[6] | (hs[7] << 16);
  ol.x = ls[0] | (ls[1] << 16); ol.y = ls[2] | (ls[3] << 16);
  ol.z = ls[4] | (ls[5] << 16); ol.w = ls[6] | (ls[7] << 16);
  ((uint4*)Dh)[i] = oh;
  ((uint4*)Dl)[i] = ol;
}

// ---------- fp32[R,C] -> (hi,lo) bf16[C,R] transpose-split, 32x32 tiles ----------
__global__ __launch_bounds__(256) void splitT_kernel(const float* __restrict__ S, int R, int C,
    long long sS, unsigned short* __restrict__ Dh, unsigned short* __restrict__ Dl, long long sD)
{
  __shared__ float t[32][33];
  const int bz = blockIdx.z;
  S += sS * bz;  Dh += sD * bz;  Dl += sD * bz;
  const int c0 = blockIdx.x * 32, r0 = blockIdx.y * 32;
  const int tx = threadIdx.x & 31, ty = threadIdx.x >> 5;
  #pragma unroll
  for (int i = 0; i < 4; i++) t[ty + 8 * i][tx] = S[(size_t)(r0 + ty + 8 * i) * C + c0 + tx];
  __syncthreads();
  #pragma unroll
  for (int i = 0; i < 4; i++) {
    const int c = ty + 8 * i;
    const float x = t[tx][c];
    const unsigned short h = f2bf(x);
    Dh[(size_t)(c0 + c) * R + r0 + tx] = h;
    Dl[(size_t)(c0 + c) * R + r0 + tx] = f2bf(x - bf2f(h));
  }
}

// ---------- split-bf16 MFMA GEMM: C[M,N] = A[M,K] * B[N,K]^T  (~fp32 accuracy) ----------
// A,B given as (hi,lo) bf16 pairs, row-major K-contiguous.
// acc += Ahi*Bhi + Ahi*Blo + Alo*Bhi  (Alo*Blo ~1.6e-5 rel, dropped).
// 64x64 tile, 4 waves (each 32x32 via 2x2 mfma_f32_16x16x32_bf16).
// BIAS: 0 none, 1 col fp32*bscale, 2 per-batch row fp32. OUTM: 0 fp32, 1 split pair.
template<int BIAS, bool RELU, int OUTM>
__global__ __launch_bounds__(256) void mgemm_kernel(
    const unsigned short* __restrict__ Ah, const unsigned short* __restrict__ Al, int lda, long long sA,
    const unsigned short* __restrict__ Bh, const unsigned short* __restrict__ Bl, int ldb, long long sB,
    void* __restrict__ C0, void* __restrict__ C1, int ldc, long long sC,
    int K, const float* __restrict__ bias, int sBias, float bscale)
{
  __shared__ __align__(16) unsigned short AsH[64 * LDP];
  __shared__ __align__(16) unsigned short AsL[64 * LDP];
  __shared__ __align__(16) unsigned short BsH[64 * LDP];
  __shared__ __align__(16) unsigned short BsL[64 * LDP];
  const int bz = blockIdx.z;
  Ah += sA * bz;  Al += sA * bz;  Bh += sB * bz;  Bl += sB * bz;
  const int m0 = blockIdx.y * 64, n0 = blockIdx.x * 64;
  const int tid = threadIdx.x;
  const int lr = tid >> 2, lc = (tid & 3) * 16;      // staging: row, col16
  const int w = tid >> 6, lane = tid & 63;
  const int wm = (w >> 1) * 32, wn = (w & 1) * 32;   // wave's 32x32 quadrant
  const int fr = lane & 15, fk = (lane >> 4) * 8;    // fragment row + k-base
  const f32x4 zz = {0.f, 0.f, 0.f, 0.f};
  f32x4 acc[2][2] = {{zz, zz}, {zz, zz}};
  const size_t abase = (size_t)(m0 + lr) * lda + lc;
  const size_t bbase = (size_t)(n0 + lr) * ldb + lc;
  uint4 ah0 = *(const uint4*)(Ah + abase), ah1 = *(const uint4*)(Ah + abase + 8);
  uint4 al0 = *(const uint4*)(Al + abase), al1 = *(const uint4*)(Al + abase + 8);
  uint4 bh0 = *(const uint4*)(Bh + bbase), bh1 = *(const uint4*)(Bh + bbase + 8);
  uint4 bl0 = *(const uint4*)(Bl + bbase), bl1 = *(const uint4*)(Bl + bbase + 8);
  const int NT = K >> 6;
  for (int t = 0; t < NT; ++t) {
    __syncthreads();
    *(uint4*)&AsH[lr * LDP + lc] = ah0;  *(uint4*)&AsH[lr * LDP + lc + 8] = ah1;
    *(uint4*)&AsL[lr * LDP + lc] = al0;  *(uint4*)&AsL[lr * LDP + lc + 8] = al1;
    *(uint4*)&BsH[lr * LDP + lc] = bh0;  *(uint4*)&BsH[lr * LDP + lc + 8] = bh1;
    *(uint4*)&BsL[lr * LDP + lc] = bl0;  *(uint4*)&BsL[lr * LDP + lc + 8] = bl1;
    __syncthreads();
    if (t + 1 < NT) {   // prefetch next K-tile while computing this one
      const size_t ka = abase + (size_t)(t + 1) * 64;
      const size_t kb = bbase + (size_t)(t + 1) * 64;
      ah0 = *(const uint4*)(Ah + ka);  ah1 = *(const uint4*)(Ah + ka + 8);
      al0 = *(const uint4*)(Al + ka);  al1 = *(const uint4*)(Al + ka + 8);
      bh0 = *(const uint4*)(Bh + kb);  bh1 = *(const uint4*)(Bh + kb + 8);
      bl0 = *(const uint4*)(Bl + kb);  bl1 = *(const uint4*)(Bl + kb + 8);
    }
    #pragma unroll
    for (int ks = 0; ks < 2; ++ks) {
      const bf16x8 aH0 = *(const bf16x8*)&AsH[(wm + fr) * LDP + ks * 32 + fk];
      const bf16x8 aH1 = *(const bf16x8*)&AsH[(wm + 16 + fr) * LDP + ks * 32 + fk];
      const bf16x8 aL0 = *(const bf16x8*)&AsL[(wm + fr) * LDP + ks * 32 + fk];
      const bf16x8 aL1 = *(const bf16x8*)&AsL[(wm + 16 + fr) * LDP + ks * 32 + fk];
      const bf16x8 bH0 = *(const bf16x8*)&BsH[(wn + fr) * LDP + ks * 32 + fk];
      const bf16x8 bH1 = *(const bf16x8*)&BsH[(wn + 16 + fr) * LDP + ks * 32 + fk];
      const bf16x8 bL0 = *(const bf16x8*)&BsL[(wn + fr) * LDP + ks * 32 + fk];
      const bf16x8 bL1 = *(const bf16x8*)&BsL[(wn + 16 + fr) * LDP + ks * 32 + fk];
      acc[0][0] = __builtin_amdgcn_mfma_f32_16x16x32_bf16(aH0, bH0, acc[0][0], 0, 0, 0);
      acc[0][1] = __builtin_amdgcn_mfma_f32_16x16x32_bf16(aH0, bH1, acc[0][1], 0, 0, 0);
      acc[1][0] = __builtin_amdgcn_mfma_f32_16x16x32_bf16(aH1, bH0, acc[1][0], 0, 0, 0);
      acc[1][1] = __builtin_amdgcn_mfma_f32_16x16x32_bf16(aH1, bH1, acc[1][1], 0, 0, 0);
      acc[0][0] = __builtin_amdgcn_mfma_f32_16x16x32_bf16(aH0, bL0, acc[0][0], 0, 0, 0);
      acc[0][1] = __builtin_amdgcn_mfma_f32_16x16x32_bf16(aH0, bL1, acc[0][1], 0, 0, 0);
      acc[1][0] = __builtin_amdgcn_mfma_f32_16x16x32_bf16(aH1, bL0, acc[1][0], 0, 0, 0);
      acc[1][1] = __builtin_amdgcn_mfma_f32_16x16x32_bf16(aH1, bL1, acc[1][1], 0, 0, 0);
      acc[0][0] = __builtin_amdgcn_mfma_f32_16x16x32_bf16(aL0, bH0, acc[0][0], 0, 0, 0);
      acc[0][1] = __builtin_amdgcn_mfma_f32_16x16x32_bf16(aL0, bH1, acc[0][1], 0, 0, 0);
      acc[1][0] = __builtin_amdgcn_mfma_f32_16x16x32_bf16(aL1, bH0, acc[1][0], 0, 0, 0);
      acc[1][1] = __builtin_amdgcn_mfma_f32_16x16x32_bf16(aL1, bH1, acc[1][1], 0, 0, 0);
    }
  }
  const long long cb = sC * bz;
  #pragma unroll
  for (int fi = 0; fi < 2; ++fi) {
    #pragma unroll
    for (int r = 0; r < 4; ++r) {
      const int m = m0 + wm + fi * 16 + (lane >> 4) * 4 + r;   // C/D row (m89-verified)
      float rb = 0.f;
      if (BIAS == 2) rb = bias[(size_t)sBias * bz + m];
      #pragma unroll
      for (int fj = 0; fj < 2; ++fj) {
        const int n = n0 + wn + fj * 16 + fr;                  // C/D col = lane&15
        float val = acc[fi][fj][r];
        if (BIAS == 1) val += bscale * bias[n];
        if (BIAS == 2) val += rb;
        if (RELU) val = fmaxf(val, 0.f);
        if (OUTM == 0) {
          ((float*)C0)[cb + (size_t)m * ldc + n] = val;
        } else {
          const unsigned short h = f2bf(val);
          ((unsigned short*)C0)[cb + (size_t)m * ldc + n] = h;
          ((unsigned short*)C1)[cb + (size_t)m * ldc + n] = f2bf(val - bf2f(h));
        }
      }
    }
  }
}

// ---------- row softmax (masked) + Kc = exp(10*(S-1)) compacted only ----------
__global__ __launch_bounds__(256) void softmax_kernel(
    const float* __restrict__ QK, const int* __restrict__ Ms,
    const int* __restrict__ pos, float* __restrict__ Kc)
{
  const int r = blockIdx.x;          // 0..2047 (b*128+t)
  const int b = r >> 7;
  const int tid = threadIdx.x;
  const float4 x = *(const float4*)(QK + (size_t)r * HW_DIM + tid * 4);
  const int4 m4 = *(const int4*)(Ms + b * HW_DIM + tid * 4);
  float mx = -3.0e38f;
  if (m4.x) mx = x.x;
  if (m4.y) mx = fmaxf(mx, x.y);
  if (m4.z) mx = fmaxf(mx, x.z);
  if (m4.w) mx = fmaxf(mx, x.w);
  #pragma unroll
  for (int o = 32; o; o >>= 1) mx = fmaxf(mx, __shfl_xor(mx, o));
  __shared__ float red[4];
  const int lane = tid & 63, w = tid >> 6;
  if (lane == 0) red[w] = mx;
  __syncthreads();
  const float gmax = fmaxf(fmaxf(red[0], red[1]), fmaxf(red[2], red[3]));
  __syncthreads();
  const float e0 = m4.x ? __expf(x.x - gmax) : 0.f;
  const float e1 = m4.y ? __expf(x.y - gmax) : 0.f;
  const float e2 = m4.z ? __expf(x.z - gmax) : 0.f;
  const float e3 = m4.w ? __expf(x.w - gmax) : 0.f;
  float s = e0 + e1 + e2 + e3;
  #pragma unroll
  for (int o = 32; o; o >>= 1) s += __shfl_xor(s, o);
  if (lane == 0) red[w] = s;
  __syncthreads();
  const float inv = 1.0f / (red[0] + red[1] + red[2] + red[3]);
  const int4 p4 = *(const int4*)(pos + b * HW_DIM + tid * 4);
  const float ev[4] = {e0, e1, e2, e3};
  const int pp[4] = {p4.x, p4.y, p4.z, p4.w};
  #pragma unroll
  for (int q = 0; q < 4; q++)
    if (pp[q] >= 0) Kc[(size_t)r * HW_DIM + pp[q]] = __expf(fmaf(10.f, ev[q] * inv, -10.f));
}

// ---------- Sinkhorn: identical to the round-5/6 PASS version ----------
__global__ __launch_bounds__(1024, 4) void sinkhorn_kernel(
    const float* __restrict__ Kc, const int* __restrict__ nfg_arr,
    const int* __restrict__ pos, const int* __restrict__ maxIter,
    float* __restrict__ u_out, float* __restrict__ v_out)
{
  const int b = blockIdx.x;
  const int tid = threadIdx.x;
  const int tg = tid >> 6, kg = tid & 63;
  const int nfg = nfg_arr[b];
  const float inv_nfg = 1.0f / (float)nfg;
  const int niter = *maxIter;
  const int njall = (nfg + 63) >> 6;
  __shared__ float part[16][PARTC];
  __shared__ float v_s[HW_DIM];
  __shared__ float u_s[T_DIM];
  __shared__ int conv;
  const float* KB = Kc + (size_t)(b * T_DIM) * HW_DIM;

  if (njall * 64 <= PARTC) {
    const int njr = (njall < NJR) ? njall : NJR;
    float kreg[8][NJR];
    #pragma unroll
    for (int j = 0; j < NJR; j++) {
      #pragma unroll
      for (int i = 0; i < 8; i++) {
        const int col = kg + 64 * j;
        float vle = 0.f;
        if (j < njr && col < nfg) vle = KB[(size_t)(tg * 8 + i) * HW_DIM + col];
        kreg[i][j] = vle;
      }
    }
    if (tid < T_DIM) u_s[tid] = 1.0f / 128.0f;
    if (tid == 0) conv = 1;
    const float bv = (tid < nfg) ? inv_nfg : 0.f;
    float u_prev = 1.0f / 128.0f;
    __syncthreads();

    for (int it = 0; it < niter; ++it) {
      float uu[8];
      #pragma unroll
      for (int i = 0; i < 8; i++) uu[i] = u_s[tg * 8 + i];
      #pragma unroll
      for (int j = 0; j < NJR; j++) {
        if (j < njr) {
          float s = 0.f;
          #pragma unroll
          for (int i = 0; i < 8; i++) s = fmaf(kreg[i][j], uu[i], s);
          part[tg][kg + 64 * j] = s;
        }
      }
      for (int j = NJR; j < njall; ++j) {
        const int col = kg + 64 * j;
        float s = 0.f;
        #pragma unroll
        for (int i = 0; i < 8; i++) {
          const float kk = (col < nfg) ? KB[(size_t)(tg * 8 + i) * HW_DIM + col] : 0.f;
          s = fmaf(kk, uu[i], s);
        }
        part[tg][col] = s;
      }
      __syncthreads();                                        // B1
      if (it != 0 && (it % CHK) == 0) {
        if (conv) break;
      }
      const int checknow = ((it % CHK) == (CHK - 1));
      if (checknow && tid == 0) conv = 1;
      {
        float vv = 0.f;
        if (tid < nfg) {
          float s = 0.f;
          #pragma unroll
          for (int g = 0; g < 16; g++) s += part[g][tid];
          vv = bv * fast_rcp(s);
        }
        v_s[tid] = vv;
      }
      __syncthreads();                                        // B2
      float vload[NJR];
      #pragma unroll
      for (int j = 0; j < NJR; j++) vload[j] = (j < njr) ? v_s[kg + 64 * j] : 0.f;
      float kv[8];
      #pragma unroll
      for (int i = 0; i < 8; i++) {
        float s = 0.f;
        #pragma unroll
        for (int j = 0; j < NJR; j++) s = fmaf(kreg[i][j], vload[j], s);
        kv[i] = s;
      }
      for (int j = NJR; j < njall; ++j) {
        const int col = kg + 64 * j;
        const float vv = v_s[col];
        #pragma unroll
        for (int i = 0; i < 8; i++) {
          const float kk = (col < nfg) ? KB[(size_t)(tg * 8 + i) * HW_DIM + col] : 0.f;
          kv[i] = fmaf(kk, vv, kv[i]);
        }
      }
      float k2[4];
      #pragma unroll
      for (int p = 0; p < 4; p++) {
        const float g = (kg & 1) ? kv[2 * p] : kv[2 * p + 1];
        const float r = __shfl_xor(g, 1);
        k2[p] = ((kg & 1) ? kv[2 * p + 1] : kv[2 * p]) + r;
      }
      float k3[2];
      #pragma unroll
      for (int q = 0; q < 2; q++) {
        const float g = (kg & 2) ? k2[2 * q] : k2[2 * q + 1];
        const float r = __shfl_xor(g, 2);
        k3[q] = ((kg & 2) ? k2[2 * q + 1] : k2[2 * q]) + r;
      }
      float t;
      {
        const float g = (kg & 4) ? k3[0] : k3[1];
        const float r = __shfl_xor(g, 4);
        t = ((kg & 4) ? k3[1] : k3[0]) + r;
      }
      t += __shfl_xor(t, 8);
      t += __shfl_xor(t, 16);
      t += __shfl_xor(t, 32);
      const float u_new = 0.0078125f * fast_rcp(t);
      if (kg < 8) u_s[tg * 8 + kg] = u_new;
      if (checknow) {
        const int ok = (fabsf(u_new - u_prev) <= TOL * fabsf(u_new));
        if (!__all(ok) && kg == 0) conv = 0;
      }
      u_prev = u_new;
    }
    __syncthreads();
    if (tid < T_DIM) u_out[b * T_DIM + tid] = u_s[tid];
    {
      const int p = pos[b * HW_DIM + tid];
      v_out[b * HW_DIM + tid] = (p >= 0) ? v_s[p] : 0.f;
    }
  } else {
    if (tid < T_DIM) u_s[tid] = 1.0f / 128.0f;
    const float bv = (tid < nfg) ? inv_nfg : 0.f;
    __syncthreads();
    for (int it = 0; it < niter; ++it) {
      float vv = 0.f;
      if (tid < nfg) {
        float s = 0.f;
        for (int t = 0; t < T_DIM; t++) s = fmaf(KB[(size_t)t * HW_DIM + tid], u_s[t], s);
        vv = bv * fast_rcp(s);
      }
      v_s[tid] = vv;
      __syncthreads();
      #pragma unroll
      for (int r8 = 0; r8 < 8; r8++) {
        const int r = tg * 8 + r8;
        float s = 0.f;
        for (int j = 0; j < 16; j++) {
          const int col = kg + 64 * j;
          if (col < nfg) s = fmaf(KB[(size_t)r * HW_DIM + col], v_s[col], s);
        }
        #pragma unroll
        for (int o = 32; o; o >>= 1) s += __shfl_xor(s, o);
        if (kg == 0) u_s[r] = 0.0078125f * fast_rcp(s);
      }
      __syncthreads();
    }
    if (tid < T_DIM) u_out[b * T_DIM + tid] = u_s[tid];
    const int p = pos[b * HW_DIM + tid];
    v_out[b * HW_DIM + tid] = (p >= 0) ? v_s[p] : 0.f;
  }
}

// ---------- S_hat = u * Km * v  (gathered from compacted Kc), split bf16 out ----------
__global__ __launch_bounds__(256) void shat_kernel(const float* __restrict__ Kc,
    const int* __restrict__ pos, const float* __restrict__ u, const float* __restrict__ v,
    unsigned short* __restrict__ ShH, unsigned short* __restrict__ ShL)
{
  const int r = blockIdx.x, b = r >> 7, tid = threadIdx.x;
  const float uu = u[r];
  const int4 p4 = *(const int4*)(pos + b * HW_DIM + tid * 4);
  const float4 vv = *(const float4*)(v + (size_t)b * HW_DIM + tid * 4);
  const float* kr = Kc + (size_t)r * HW_DIM;
  const float ov[4] = {
    (p4.x >= 0) ? uu * kr[p4.x] * vv.x : 0.f,
    (p4.y >= 0) ? uu * kr[p4.y] * vv.y : 0.f,
    (p4.z >= 0) ? uu * kr[p4.z] * vv.z : 0.f,
    (p4.w >= 0) ? uu * kr[p4.w] * vv.w : 0.f };
  unsigned hs[4], ls[4];
  #pragma unroll
  for (int q = 0; q < 4; q++) {
    const unsigned short h = f2bf(ov[q]);
    hs[q] = h;  ls[q] = f2bf(ov[q] - bf2f(h));
  }
  uint2 ph, pl;
  ph.x = hs[0] | (hs[1] << 16);  ph.y = hs[2] | (hs[3] << 16);
  pl.x = ls[0] | (ls[1] << 16);  pl.y = ls[2] | (ls[3] << 16);
  *(uint2*)(ShH + (size_t)r * HW_DIM + tid * 4) = ph;
  *(uint2*)(ShL + (size_t)r * HW_DIM + tid * 4) = pl;
}

extern "C" void kernel_launch(void* const* d_in, const int* in_sizes, int n_in,
                              void* d_out, int out_size, void* d_ws, size_t ws_size,
                              hipStream_t stream)
{
  const float* F_a  = (const float*)d_in[0];
  const float* F_s  = (const float*)d_in[1];
  const int*   M_s  = (const int*)  d_in[2];
  const float* W_aQ = (const float*)d_in[3];
  const float* b_aQ = (const float*)d_in[4];
  const float* W_sK = (const float*)d_in[5];
  const float* b_sK = (const float*)d_in[6];
  const float* W_sV = (const float*)d_in[7];
  const float* b_sV = (const float*)d_in[8];
  const float* W1   = (const float*)d_in[9];
  const float* b1   = (const float*)d_in[10];
  const float* W2   = (const float*)d_in[11];
  const float* b2   = (const float*)d_in[12];
  const int* maxIter = (const int*)d_in[13];
  float* out = (float*)d_out;

  // ---- fp32 workspace (ws_size ~268 MB; everything gets its own region) ----
  float* f = (float*)d_ws;
  float* w0 = f;  f += 256;
  float* wq = f;  f += 256;
  float* s0 = f;  f += 4;
  float* qb = f;  f += 2048;
  float* u  = f;  f += 2048;
  float* v  = f;  f += 16 * 1024;
  int* nfg  = (int*)f;  f += 16;
  int* pos  = (int*)f;  f += 16 * 1024;
  float* QK = f;  f += 2048 * 1024;
  float* Kc = f;  f += 2048 * 1024;
  // ---- bf16 (hi,lo) pairs ----
  unsigned short* us = (unsigned short*)f;
  #define ALLOC2(name, n) unsigned short* name##H = us; us += (n); unsigned short* name##L = us; us += (n);
  ALLOC2(F_a_,  2048 * 256)
  ALLOC2(W_sK_, 256 * 1024)
  ALLOC2(W_aQ_, 256 * 1024)
  ALLOC2(F_s_,  16 * 1024 * 256)
  ALLOC2(F_sT_, 16 * 256 * 1024)
  ALLOC2(MmT_,  256 * 256)
  ALLOC2(W_sVT_, 256 * 256)
  ALLOC2(W1T_, 768 * 256)
  ALLOC2(W2T_, 256 * 768)
  ALLOC2(P_,   2048 * 256)
  ALLOC2(Sh_,  2048 * 1024)
  ALLOC2(A2_,  2048 * 256)
  ALLOC2(o1_,  2048 * 256)
  ALLOC2(hh_,  2048 * 768)
  #undef ALLOC2

  // mask prep + fp32 bias folds
  prep_kernel<<<16, 256, 0, stream>>>(M_s, nfg, pos);
  wvec_kernel<<<129, 256, 0, stream>>>(W_aQ, b_aQ, W_sK, b_sK, w0, wq, s0);
  qb_kernel<<<512, 256, 0, stream>>>(F_a, wq, s0, qb);

  // bf16 split conversions
  split_kernel<<<256, 256, 0, stream>>>(F_a, F_a_H, F_a_L, 2048 * 256 / 8);
  split_kernel<<<128, 256, 0, stream>>>(W_sK, W_sK_H, W_sK_L, 256 * 1024 / 8);
  split_kernel<<<128, 256, 0, stream>>>(W_aQ, W_aQ_H, W_aQ_L, 256 * 1024 / 8);
  split_kernel<<<2048, 256, 0, stream>>>(F_s, F_s_H, F_s_L, 16 * 1024 * 256 / 8);
  splitT_kernel<<<dim3(8, 8, 1),  256, 0, stream>>>(W_sV, 256, 256, 0, W_sVT_H, W_sVT_L, 0);
  splitT_kernel<<<dim3(24, 8, 1), 256, 0, stream>>>(W1, 256, 768, 0, W1T_H, W1T_L, 0);
  splitT_kernel<<<dim3(8, 24, 1), 256, 0, stream>>>(W2, 768, 256, 0, W2T_H, W2T_L, 0);
  splitT_kernel<<<dim3(8, 32, 16), 256, 0, stream>>>(F_s, 1024, 256, 1024 * 256, F_sT_H, F_sT_L, 256 * 1024);

  // MmT = W_sK x W_aQ^T   [256,256] K=1024  (split out)
  mgemm_kernel<0,false,1><<<dim3(4,4,1),256,0,stream>>>(
      W_sK_H, W_sK_L, 1024, 0, W_aQ_H, W_aQ_L, 1024, 0, MmT_H, MmT_L, 256, 0, 1024, nullptr, 0, 0.f);
  // P = F_a x MmT^T + w0   [2048,256] K=256  (split out)
  mgemm_kernel<1,false,1><<<dim3(4,32,1),256,0,stream>>>(
      F_a_H, F_a_L, 256, 0, MmT_H, MmT_L, 256, 0, P_H, P_L, 256, 0, 256, w0, 0, 1.0f);
  // QK[b] = P[b] x F_s[b]^T + qb  [128,1024] K=256  (fp32 out)
  mgemm_kernel<2,false,0><<<dim3(16,2,16),256,0,stream>>>(
      P_H, P_L, 256, 128*256, F_s_H, F_s_L, 256, 1024*256, QK, nullptr, 1024, 128LL*1024, 256, qb, 128, 0.f);

  softmax_kernel<<<2048, 256, 0, stream>>>(QK, M_s, pos, Kc);
  sinkhorn_kernel<<<16, 1024, 0, stream>>>(Kc, nfg, pos, maxIter, u, v);
  shat_kernel<<<2048, 256, 0, stream>>>(Kc, pos, u, v, Sh_H, Sh_L);

  // A2[b] = Sh[b] x F_sT[b]^T   [128,256] K=1024  (split out)
  mgemm_kernel<0,false,1><<<dim3(4,2,16),256,0,stream>>>(
      Sh_H, Sh_L, 1024, 128*1024, F_sT_H, F_sT_L, 1024, 256*1024, A2_H, A2_L, 256, 128LL*256, 1024, nullptr, 0, 0.f);
  // o1 = A2 x W_sVT^T + (1/T) b_sV   [2048,256] K=256  (split out)
  mgemm_kernel<1,false,1><<<dim3(4,32,1),256,0,stream>>>(
      A2_H, A2_L, 256, 0, W_sVT_H, W_sVT_L, 256, 0, o1_H, o1_L, 256, 0, 256, b_sV, 0, 0.0078125f);
  // hh = relu(o1 x W1T^T + b1)   [2048,768] K=256  (split out)
  mgemm_kernel<1,true,1><<<dim3(12,32,1),256,0,stream>>>(
      o1_H, o1_L, 256, 0, W1T_H, W1T_L, 256, 0, hh_H, hh_L, 768, 0, 256, b1, 0, 1.0f);
  // out = hh x W2T^T + b2   [2048,256] K=768  (fp32 out)
  mgemm_kernel<1,false,0><<<dim3(4,32,1),256,0,stream>>>(
      hh_H, hh_L, 768, 0, W2T_H, W2T_L, 768, 0, out, nullptr, 256, 0, 768, b2, 0, 1.0f);
}